// Round 1
// baseline (78.798 us; speedup 1.0000x reference)
//
#include <hip/hip_runtime.h>
#include <math.h>

#define BSZ   256
#define DIN   512
#define DOUT  64
#define NQK   16   // Q*K = 4*4

// ws layout (floats):
//   SJ [256*16] @ 0       sin(C[j,q]*k)
//   CJ [256*16] @ 4096    cos(C[j,q]*k)
//   SI [256*16] @ 8192    sin(w[q]*t[i]*k)
//   CI [256*16] @ 12288   cos(w[q]*t[i]*k)
//   AP [64*16]  @ 16384   A*cos(Bp)
//   BQ [64*16]  @ 17408   A*sin(Bp)
// total 18432 floats = 73728 bytes

__global__ __launch_bounds__(256) void prep_kernel(
    const float* __restrict__ X0, const float* __restrict__ t,
    const float* __restrict__ Wc_w, const float* __restrict__ Wc_b,
    const float* __restrict__ w, const float* __restrict__ A,
    const float* __restrict__ Bp, float* __restrict__ ws)
{
    float* SJ = ws;
    float* CJ = ws + 4096;
    float* SI = ws + 8192;
    float* CI = ws + 12288;
    float* AP = ws + 16384;
    float* BQ = ws + 17408;

    const int j    = blockIdx.x;      // doubles as i-index and (if <64) o-index
    const int tid  = threadIdx.x;
    const int lane = tid & 63;
    const int q    = tid >> 6;        // wave id = q (4 waves)

    // ---- i-side table (i = blockIdx): SI/CI[i*16 + q*4 + (k-1)] ----
    if (tid < 16) {
        const int qq = tid >> 2;
        const int kk = (tid & 3) + 1;
        float arg = w[qq] * t[j] * (float)kk;
        float s, c;
        sincosf(arg, &s, &c);
        SI[j * 16 + tid] = s;
        CI[j * 16 + tid] = c;
    }

    // ---- weight fold (o = blockIdx < 64): AP/BQ[o*16 + qk] ----
    if (j < DOUT && tid >= 64 && tid < 80) {
        const int qk = tid - 64;
        float a = A[j * 16 + qk];
        float b = Bp[j * 16 + qk];
        float sb, cb;
        sincosf(b, &sb, &cb);
        AP[j * 16 + qk] = a * cb;
        BQ[j * 16 + qk] = a * sb;
    }

    // ---- C[j][q] = dot(X0[j,:], Wc_w[q,:]) + Wc_b[q], wave q per q ----
    const float* xrow = X0 + (size_t)j * DIN;
    const float* wrow = Wc_w + (size_t)q * DIN;
    float part = 0.f;
#pragma unroll
    for (int m = 0; m < DIN / 64; ++m)
        part += xrow[lane + 64 * m] * wrow[lane + 64 * m];
    // full-wave butterfly reduce (all lanes end with the sum)
#pragma unroll
    for (int off = 32; off > 0; off >>= 1)
        part += __shfl_xor(part, off, 64);
    float cval = part + Wc_b[q];

    // lanes 0..3 emit k = 1..4
    if (lane < 4) {
        float arg = cval * (float)(lane + 1);
        float s, c;
        sincosf(arg, &s, &c);
        SJ[j * 16 + q * 4 + lane] = s;
        CJ[j * 16 + q * 4 + lane] = c;
    }
}

// grid 1024 x 256 threads. block b: i = b>>2, j-range = (b&3)*64 .. +64.
// wave w handles 16 j's; lane = o (coalesced stores).
__global__ __launch_bounds__(256) void main_kernel(
    const float* __restrict__ ws, float* __restrict__ out)
{
    const float* SJ = ws;
    const float* CJ = ws + 4096;
    const float* SI = ws + 8192;
    const float* CI = ws + 12288;
    const float* AP = ws + 16384;
    const float* BQ = ws + 17408;

    const int b   = blockIdx.x;
    const int i   = b >> 2;
    const int jb0 = (b & 3) * 64;
    const int tid = threadIdx.x;
    const int o   = tid & 63;
    const int wv  = __builtin_amdgcn_readfirstlane(tid >> 6);  // SGPR wave id
    const int jbase = jb0 + wv * 16;

    // per-lane folded weights for this o
    float ap[NQK], bq[NQK];
    {
        const float4* a4 = (const float4*)(AP + o * NQK);
        const float4* b4 = (const float4*)(BQ + o * NQK);
#pragma unroll
        for (int m = 0; m < 4; ++m) {
            float4 va = a4[m], vb = b4[m];
            ap[4 * m + 0] = va.x; ap[4 * m + 1] = va.y;
            ap[4 * m + 2] = va.z; ap[4 * m + 3] = va.w;
            bq[4 * m + 0] = vb.x; bq[4 * m + 1] = vb.y;
            bq[4 * m + 2] = vb.z; bq[4 * m + 3] = vb.w;
        }
    }

    // fold the (block-uniform) i-side phases into the weights:
    // P = AP*ci - BQ*si ; Q = AP*si + BQ*ci
    float P[NQK], Qc[NQK];
#pragma unroll
    for (int qk = 0; qk < NQK; ++qk) {
        float si = SI[i * NQK + qk];
        float ci = CI[i * NQK + qk];
        P[qk]  = ap[qk] * ci - bq[qk] * si;
        Qc[qk] = ap[qk] * si + bq[qk] * ci;
    }

    float* outb = out + ((size_t)(i * 256 + jbase)) * 64 + o;

#pragma unroll 4
    for (int jj = 0; jj < 16; ++jj) {
        const float4* sj4 = (const float4*)(SJ + (jbase + jj) * NQK);
        const float4* cj4 = (const float4*)(CJ + (jbase + jj) * NQK);
        float acc = 0.f;
#pragma unroll
        for (int m = 0; m < 4; ++m) {
            float4 vs = sj4[m], vc = cj4[m];
            acc += P[4 * m + 0] * vs.x + Qc[4 * m + 0] * vc.x;
            acc += P[4 * m + 1] * vs.y + Qc[4 * m + 1] * vc.y;
            acc += P[4 * m + 2] * vs.z + Qc[4 * m + 2] * vc.z;
            acc += P[4 * m + 3] * vs.w + Qc[4 * m + 3] * vc.w;
        }
        outb[jj * 64] = acc;
    }
}

extern "C" void kernel_launch(void* const* d_in, const int* in_sizes, int n_in,
                              void* d_out, int out_size, void* d_ws, size_t ws_size,
                              hipStream_t stream) {
    const float* X0   = (const float*)d_in[0];
    const float* t    = (const float*)d_in[1];
    const float* Wc_w = (const float*)d_in[2];
    const float* Wc_b = (const float*)d_in[3];
    const float* w    = (const float*)d_in[4];
    const float* A    = (const float*)d_in[5];
    const float* Bp   = (const float*)d_in[6];
    float* out = (float*)d_out;
    float* ws  = (float*)d_ws;

    prep_kernel<<<dim3(BSZ), dim3(256), 0, stream>>>(X0, t, Wc_w, Wc_b, w, A, Bp, ws);
    main_kernel<<<dim3(1024), dim3(256), 0, stream>>>(ws, out);
}